// Round 7
// baseline (5096.468 us; speedup 1.0000x reference)
//
#include <hip/hip_runtime.h>
#include <hip/hip_bf16.h>
#include <stdint.h>

// ---------------------------------------------------------------------------
// LSTM: B=64, S=512, D_IN=1024, HID=4096, HS=1024, fp32 in/out.
//   1) cvt x, wx, wh -> bf16
//   2) pregemm (MFMA bf16, 128x128 tile): xg2 = x@wx.T + bx + bh, bf16,
//      recurrence-friendly layout [t][wg256][bloc16][n64]  (R3-identical)
//   3) persistent recurrent kernel, R10: MERGED 1024-THREAD WGs + LDS
//      h-broadcast. 64 WGs x 16 waves; 4 groups x 16 WGs; WG covers 16
//      batches x 64 h-cols. Per step the WG loads the group's 16x1024
//      h-panel ONCE into LDS (wave wv loads exactly producer-WG wv's 64-col
//      block, so the poll->load dependency is wave-local); 16 waves
//      (kq x jq = K-quarter x col-quarter) consume it from LDS. This cuts
//      device h-traffic 8MB -> 2MB/step and pollers-per-flag 64 -> 16 --
//      attacking the LLC-contention term that inflates every round trip.
//      Transport = R8-proven: sc0+sc1 ops only, per-wave flags (producer
//      wave drains ONLY its own h' stores then publishes), embedded-vmcnt
//      poll, register-tied drains. NO XCC_ID / sc0-only anywhere (3/3 runs
//      containing it failed; reverted permanently).
//      Safety: wave-flag >= t  =>  that wave passed barrier-2 of its step
//      t-1 => ALL its WG's waves completed their stage-reads of buf[t-1]
//      (tied vmcnt before ds_write before barrier-1 <= barrier-2). The 16
//      consumer waves' poll sets jointly cover all 256 producer-wave flags
//      of the group and join at barrier-1 before any h' write => WAR+RAW
//      safe. Barrier-1 also guards gpart WAR across steps.
//      t=0: gates = xg directly (no poll, no h-load, hbuf never zeroed).
//      out store + xg prefetch after the flag publish (R8).
// R3 fix retained: register-tied s_waitcnt between asm loads and use.
// ---------------------------------------------------------------------------

typedef __attribute__((ext_vector_type(8))) short short8;
typedef __attribute__((ext_vector_type(4))) float floatx4;

#define S_LEN 512
#define BATCH 64
#define DIN   1024
#define HID   4096
#define HS    1024

// workspace byte offsets (total ~336.3 MB, same footprint as R3/R8)
#define XG2_OFF   0ull                      // ushort[512*256*16*64] = 256 MB
#define XBF_OFF   268435456ull              // ushort[32768*1024]    = 64 MB
#define WXBF_OFF  335544320ull              // ushort[4096*1024]     = 8 MB
#define WHBF_OFF  343932928ull              // ushort[4096*1024]     = 8 MB
#define HBUF_OFF  352321536ull              // ushort[2][64][1024]   = 256 KB (never zeroed)
// per-wave flags: int[64*16][4] = 16 KB, aliases the FIRST 16 KB of the
// xbf region (xbf dead after pregemm; zeroed after pregemm runs).
#define FLAG_OFF  XBF_OFF

__device__ __forceinline__ unsigned short f2bf(float f) {
  unsigned int u = __float_as_uint(f);
  u += 0x7fffu + ((u >> 16) & 1u);        // RNE
  return (unsigned short)(u >> 16);
}
__device__ __forceinline__ float bf2f(unsigned short s) {
  return __uint_as_float(((unsigned int)s) << 16);
}

__device__ __forceinline__ void async_ld16(const void* g, const void* l) {
  __builtin_amdgcn_global_load_lds(
      (const __attribute__((address_space(1))) unsigned int*)g,
      (__attribute__((address_space(3))) unsigned int*)l,
      16, 0, 0);
}

// LLC-coherent (sc0 sc1) ops -- R3/R8-proven transport.
__device__ __forceinline__ short8 load16_llc(const void* p) {
  floatx4 r;
  asm volatile("global_load_dwordx4 %0, %1, off sc0 sc1"
               : "=v"(r) : "v"(p) : "memory");
  return __builtin_bit_cast(short8, r);
}
__device__ __forceinline__ void store2_llc(void* p, unsigned int v) {
  asm volatile("global_store_short %0, %1, off sc0 sc1"
               :: "v"(p), "v"(v) : "memory");
}
__device__ __forceinline__ void st4_llc(void* p, unsigned int v) {
  asm volatile("global_store_dword %0, %1, off sc0 sc1"
               :: "v"(p), "v"(v) : "memory");
}
__device__ __forceinline__ int ld_flag_llc(const int* p) {
  int v;
  asm volatile("global_load_dword %0, %1, off sc0 sc1\n\t"
               "s_waitcnt vmcnt(0)"
               : "=v"(v) : "v"(p) : "memory");
  return v;
}

__device__ __forceinline__ float sigmoidf_(float x) {
  return 1.0f / (1.0f + __expf(-x));
}
__device__ __forceinline__ float tanhf_(float x) {
  return 2.0f / (1.0f + __expf(-2.0f * x)) - 1.0f;
}

// --------------------------- fp32 -> bf16 cast ------------------------------
__global__ void cvt_kernel(const float* __restrict__ src,
                           unsigned short* __restrict__ dst, int n4) {
  int i = blockIdx.x * blockDim.x + threadIdx.x;
  if (i < n4) {
    float4 v = ((const float4*)src)[i];
    ushort4 o;
    o.x = f2bf(v.x); o.y = f2bf(v.y); o.z = f2bf(v.z); o.w = f2bf(v.w);
    ((ushort4*)dst)[i] = o;
  }
}

__global__ void zero_kernel(unsigned int* __restrict__ p, int n) {
  int i = blockIdx.x * blockDim.x + threadIdx.x;
  if (i < n) p[i] = 0u;
}

// ------------------------------- pre-GEMM -----------------------------------
// C[m][g] = sum_k x_bf[m][k] * wx_bf[g][k] + bx[g] + bh[g]   (m = b*512 + t)
// stored bf16 at xg2[((t*256 + owg)*16 + bloc)*64 + n],
//   owg = (b>>4)*64 + ((g&1023)>>4),  bloc = b&15,  n = (g>>10)*16 + (g&15)
// (identical to R3's proven kernel)
__global__ __launch_bounds__(256) void pregemm_kernel(
    const unsigned short* __restrict__ A,    // [32768][1024] bf16
    const unsigned short* __restrict__ Bw,   // [4096][1024]  bf16 (B^T layout)
    const float* __restrict__ bx, const float* __restrict__ bh,
    unsigned short* __restrict__ xg2) {
  __shared__ unsigned short As[128 * 32];
  __shared__ unsigned short Bs[128 * 32];
  const int tid = threadIdx.x;
  const int lane = tid & 63, wv = tid >> 6;
  const int l15 = lane & 15, lq = lane >> 4;
  const int m0 = blockIdx.y * 128, n0 = blockIdx.x * 128;
  const int wm = (wv >> 1) * 64, wn = (wv & 1) * 64;

  floatx4 acc[4][4];
#pragma unroll
  for (int i = 0; i < 4; i++)
#pragma unroll
    for (int j = 0; j < 4; j++) acc[i][j] = (floatx4){0.f, 0.f, 0.f, 0.f};

  for (int k0 = 0; k0 < DIN; k0 += 32) {
#pragma unroll
    for (int q = 0; q < 2; q++) {
      const int e = (q * 256 + tid) * 8;      // element within 128x32 tile
      const int r = e >> 5, c = e & 31;
      async_ld16(A + (size_t)(m0 + r) * DIN + k0 + c, (unsigned short*)As + e);
      async_ld16(Bw + (size_t)(n0 + r) * DIN + k0 + c, (unsigned short*)Bs + e);
    }
    __syncthreads();
    short8 af[4], bfv[4];
#pragma unroll
    for (int i = 0; i < 4; i++)
      af[i] = *(const short8*)&As[(wm + i * 16 + l15) * 32 + lq * 8];
#pragma unroll
    for (int j = 0; j < 4; j++)
      bfv[j] = *(const short8*)&Bs[(wn + j * 16 + l15) * 32 + lq * 8];
#pragma unroll
    for (int i = 0; i < 4; i++)
#pragma unroll
      for (int j = 0; j < 4; j++)
        acc[i][j] = __builtin_amdgcn_mfma_f32_16x16x32_bf16(af[i], bfv[j],
                                                            acc[i][j], 0, 0, 0);
    __syncthreads();
  }

#pragma unroll
  for (int j = 0; j < 4; j++) {
    const int col = n0 + wn + j * 16 + l15;
    const float bias = bx[col] + bh[col];
    const int gate = col >> 10;
    const int c1 = col & 1023;
    const int wslice = c1 >> 4, cc = c1 & 15;
    const int n_idx = gate * 16 + cc;
#pragma unroll
    for (int i = 0; i < 4; i++) {
#pragma unroll
      for (int r = 0; r < 4; r++) {
        const int m = m0 + wm + i * 16 + lq * 4 + r;
        const int b = m >> 9, t = m & 511;
        const size_t idx =
            ((size_t)(t * 256 + ((b >> 4) * 64 + wslice)) * 16 + (b & 15)) * 64 +
            n_idx;
        xg2[idx] = f2bf(acc[i][j][r] + bias);
      }
    }
  }
}

// ------------------------------ recurrence ----------------------------------
// 64 WGs x 1024 threads = 4 groups x 16 WGs. Group g: batches [g*16,+16).
// WG w (wslice = w&15) covers h-cols [wslice*64,+64), i.e. gate-cols
// {gate*1024 + wslice*64 + c}. Waves: wv = kq + 4*jq? No: kq = wv&3
// (K-quarter, 256 cols of h), jq = wv>>2 (col-quarter, 16 of the 64 cols).
// Per wave: bfrag[4 gates][8 kc], 32 MFMA, M=16 (full batch panel).
// h-panel staged in LDS once per step; wave wv stage-loads exactly producer
// WG (group*16+wv)'s 64-col block (the block its polls gate).
__global__ __launch_bounds__(1024, 1) void lstm_kernel(
    const unsigned short* __restrict__ whbf,  // [4096][1024] bf16
    const unsigned short* __restrict__ xg2,
    unsigned short* __restrict__ hbuf,        // [2][64][1024] bf16
    int* __restrict__ flags,                  // [64*16][4] per-wave flags
    float* __restrict__ out,                  // [64][512][1024]
    float* __restrict__ outh, float* __restrict__ outc) {
  __shared__ unsigned short hstage[16 * 1032];  // h panel, padded stride
  __shared__ float gpart[4 * 16 * 260];         // [kq][batch][gc] padded

  const int tid = threadIdx.x;
  const int lane = tid & 63, wv = tid >> 6;
  const int l15 = lane & 15, lq = lane >> 4;
  const int wg = blockIdx.x;
  const int group = wg >> 4, wslice = wg & 15;
  const int kq = wv & 3, jq = wv >> 2;
  const int j0 = wslice * 64 + jq * 16;

  // B fragments: bfrag[j][kc] covers gate j, cols j0..j0+15 (within gate),
  // k = kq*256 + kc*32 + lq*8 .. +8  (AGPR/VGPR-resident)
  short8 bfrag[4][8];
#pragma unroll
  for (int j = 0; j < 4; j++) {
    const size_t grow = (size_t)(j * 1024 + j0 + l15) * HS;
#pragma unroll
    for (int kc = 0; kc < 8; kc++)
      bfrag[j][kc] = *(const short8*)&whbf[grow + kq * 256 + kc * 32 + lq * 8];
  }

  // elementwise mapping: 1024 threads = 16 batches x 64 cols; eb == wv.
  const int eb = tid >> 6;
  const int ec = tid & 63;
  const int gb = group * 16 + eb;
  float c_state = 0.0f;

  // stage-load mapping (wave wv <-> producer WG group*16+wv):
  // lane loads rows (lane>>3) and (lane>>3)+8, cols wv*64 + (lane&7)*8.
  const int srow = lane >> 3;
  const int scol = wv * 64 + (lane & 7) * 8;

  // poll: lane polls producer wave (lane&15) of producer WG (group*16+wv)
  const int* fp = flags + ((size_t)((group * 16 + wv) * 16 + (lane & 15))) * 4;
  int* myflag = flags + ((size_t)(wg * 16 + wv)) * 4;

  // xg addressing (R3 layout): owg = group*64 + wslice*4 + (ec>>4)
  const int owg = group * 64 + wslice * 4 + (ec >> 4);
  const size_t xgb0 = ((size_t)(0 * 256 + owg) * 16 + eb) * 64 + (ec & 15);
  unsigned short xv0 = xg2[xgb0], xv1 = xg2[xgb0 + 16], xv2 = xg2[xgb0 + 32],
                 xv3 = xg2[xgb0 + 48];

  for (int t = 0; t < S_LEN; t++) {
    if (t > 0) {
      // poll this wave's producer WG (16 wave-flags; embedded vmcnt(0) also
      // absorbs last step's out-store ack + xg prefetch on round 1)
      while (true) {
        int v = ld_flag_llc(fp);
        if (__all(v >= t)) break;
        __builtin_amdgcn_s_sleep(1);
      }
      // stage that producer's 64-col block: 2 x 16B per lane, LLC-coherent
      const unsigned short* hp = hbuf + (size_t)(t & 1) * (BATCH * HS);
      const size_t gr = (size_t)(group * 16 + srow) * HS + scol;
      short8 s0 = load16_llc(&hp[gr]);
      short8 s1 = load16_llc(&hp[gr + 8 * HS]);
      // Register-tied drain: ds_writes below data-depend on post-wait values
      asm volatile("s_waitcnt vmcnt(0)"
                   : "+v"(s0), "+v"(s1) :: "memory");
      *(short8*)&hstage[srow * 1032 + scol] = s0;
      *(short8*)&hstage[(srow + 8) * 1032 + scol] = s1;
    }
    __syncthreads();  // barrier 1: stage ready + joint poll cover + gpart WAR

    if (t > 0) {
      short8 a[8];
#pragma unroll
      for (int kc = 0; kc < 8; kc++)
        a[kc] = *(const short8*)&hstage[l15 * 1032 + kq * 256 + kc * 32 +
                                        lq * 8];
      floatx4 acc0 = (floatx4){0.f, 0.f, 0.f, 0.f};
      floatx4 acc1 = acc0, acc2 = acc0, acc3 = acc0;
#pragma unroll
      for (int kc = 0; kc < 8; kc++) {
        acc0 = __builtin_amdgcn_mfma_f32_16x16x32_bf16(a[kc], bfrag[0][kc], acc0, 0, 0, 0);
        acc1 = __builtin_amdgcn_mfma_f32_16x16x32_bf16(a[kc], bfrag[1][kc], acc1, 0, 0, 0);
        acc2 = __builtin_amdgcn_mfma_f32_16x16x32_bf16(a[kc], bfrag[2][kc], acc2, 0, 0, 0);
        acc3 = __builtin_amdgcn_mfma_f32_16x16x32_bf16(a[kc], bfrag[3][kc], acc3, 0, 0, 0);
      }
#pragma unroll
      for (int r = 0; r < 4; r++) {
        const int row = (kq * 16 + lq * 4 + r) * 260;
        gpart[row + 0 * 64 + jq * 16 + l15] = acc0[r];
        gpart[row + 1 * 64 + jq * 16 + l15] = acc1[r];
        gpart[row + 2 * 64 + jq * 16 + l15] = acc2[r];
        gpart[row + 3 * 64 + jq * 16 + l15] = acc3[r];
      }
    }
    __syncthreads();  // barrier 2: gpart ready

    float g0 = bf2f(xv0), g1 = bf2f(xv1), g2 = bf2f(xv2), g3 = bf2f(xv3);
    if (t > 0) {
#pragma unroll
      for (int q = 0; q < 4; q++) {
        const float* gp = &gpart[(q * 16 + eb) * 260 + ec];
        g0 += gp[0]; g1 += gp[64]; g2 += gp[128]; g3 += gp[192];
      }
    }
    const float i_ = sigmoidf_(g0);
    const float f_ = sigmoidf_(g1);
    const float gg = tanhf_(g2);
    const float o_ = sigmoidf_(g3);
    c_state = f_ * c_state + i_ * gg;
    const float h = o_ * tanhf_(c_state);

    // h' write-through to LLC (this thread's single element)
    store2_llc(&hbuf[(size_t)((t + 1) & 1) * (BATCH * HS) + (size_t)gb * HS +
                     wslice * 64 + ec],
               (unsigned int)f2bf(h));

    if (t == S_LEN - 1) {
      out[((size_t)gb * S_LEN + t) * HS + wslice * 64 + ec] = h;
      outh[(size_t)gb * HS + wslice * 64 + ec] = h;
      outc[(size_t)gb * HS + wslice * 64 + ec] = c_state;
      break;  // nobody waits on the last flag
    }

    // publish: drain THIS WAVE's h' stores only, then its wave-flag
    asm volatile("s_waitcnt vmcnt(0)" ::: "memory");
    if (lane == 0) st4_llc(myflag, (unsigned int)(t + 1));

    // xg prefetch for t+1 (plain cached; returns during next poll window)
    const size_t xgb =
        ((size_t)((t + 1) * 256 + owg) * 16 + eb) * 64 + (ec & 15);
    unsigned short nx0 = xg2[xgb], nx1 = xg2[xgb + 16], nx2 = xg2[xgb + 32],
                   nx3 = xg2[xgb + 48];

    // out store: nontemporal, off the critical path (ack drains in the
    // next step's first poll round)
    __builtin_nontemporal_store(
        h, &out[((size_t)gb * S_LEN + t) * HS + wslice * 64 + ec]);

    xv0 = nx0; xv1 = nx1; xv2 = nx2; xv3 = nx3;
  }
}

// ------------------------------- launcher -----------------------------------
extern "C" void kernel_launch(void* const* d_in, const int* in_sizes, int n_in,
                              void* d_out, int out_size, void* d_ws,
                              size_t ws_size, hipStream_t stream) {
  const float* x  = (const float*)d_in[0];
  const float* wx = (const float*)d_in[1];
  const float* wh = (const float*)d_in[2];
  const float* bx = (const float*)d_in[3];
  const float* bh = (const float*)d_in[4];
  char* ws = (char*)d_ws;
  unsigned short* xg2  = (unsigned short*)(ws + XG2_OFF);
  unsigned short* xbf  = (unsigned short*)(ws + XBF_OFF);
  unsigned short* wxbf = (unsigned short*)(ws + WXBF_OFF);
  unsigned short* whbf = (unsigned short*)(ws + WHBF_OFF);
  unsigned short* hbuf = (unsigned short*)(ws + HBUF_OFF);
  int* flags = (int*)(ws + FLAG_OFF);

  float* out  = (float*)d_out;
  float* outh = out + (size_t)BATCH * S_LEN * HS;
  float* outc = outh + BATCH * HS;

  cvt_kernel<<<(33554432 / 4) / 256, 256, 0, stream>>>(x, xbf, 33554432 / 4);
  cvt_kernel<<<(4194304 / 4) / 256, 256, 0, stream>>>(wx, wxbf, 4194304 / 4);
  cvt_kernel<<<(4194304 / 4) / 256, 256, 0, stream>>>(wh, whbf, 4194304 / 4);

  dim3 pg(HID / 128, (BATCH * S_LEN) / 128);  // 32 x 256
  pregemm_kernel<<<pg, 256, 0, stream>>>(xbf, wxbf, bx, bh, xg2);

  // zero per-wave flags (4096 uints = 16 KB) AFTER pregemm: they alias the
  // first 16 KB of the (now dead) xbf region. hbuf is never zeroed (t=0
  // computes gates directly from xg).
  zero_kernel<<<16, 256, 0, stream>>>((unsigned int*)flags, 4096);

  lstm_kernel<<<64, 1024, 0, stream>>>(whbf, xg2, hbuf, flags, out, outh, outc);
}